// Round 8
// baseline (179.558 us; speedup 1.0000x reference)
//
#include <hip/hip_runtime.h>
#include <math.h>

#define TPB 256
#define NNEG 2048
#define D 128
#define RPB 256            // rows per block (4 waves x 64)
#define NSPLIT 4           // negative-range splits
#define QSZ (NNEG / NSPLIT)   // 512 negs per block
#define NCHQ (QSZ / 64)       // 8 chunks of 64 negs
#define L2E 1.44269504088896340736f

typedef __attribute__((ext_vector_type(8))) short bf16x8;
typedef __attribute__((ext_vector_type(4))) float f32x4;

#define MFMA16 __builtin_amdgcn_mfma_f32_16x16x32_bf16

static __device__ __forceinline__ unsigned int f2bf(float f) {
    unsigned int u = __float_as_uint(f);
    return (u + 0x7FFFu + ((u >> 16) & 1u)) >> 16;
}
static __device__ __forceinline__ float bfround(float f) {
    unsigned int u = __float_as_uint(f);
    return __uint_as_float((u + 0x7FFFu + ((u >> 16) & 1u)) & 0xFFFF0000u);
}
static __device__ __forceinline__ unsigned int pk2(float x, float y) {
    return f2bf(x) | (f2bf(y) << 16);
}

static __device__ __forceinline__ void stage16(const void* g, void* l) {
    __builtin_amdgcn_global_load_lds(
        (const __attribute__((address_space(1))) unsigned int*)g,
        (__attribute__((address_space(3))) unsigned int*)l, 16, 0, 0);
}

// ---------------- clear: zero the vocab bitmap ----------------
__global__ __launch_bounds__(TPB) void sspe_clear(unsigned int* __restrict__ bm, int words) {
    const int i = blockIdx.x * TPB + threadIdx.x;
    if (i < words) bm[i] = 0u;
}

// ---------------- prep: normalize negatives -> bf16, log(samp_p), bitmap ----------------
__global__ __launch_bounds__(TPB) void sspe_prep(
    const float* __restrict__ embed,
    const float* __restrict__ sprobs,
    const int* __restrict__ sidx,
    unsigned int* __restrict__ en_bf,
    float* __restrict__ ln_samp,
    unsigned int* __restrict__ bitmap)
{
    const int t = threadIdx.x;
    const int wave = t >> 6;
    const int lane = t & 63;
    const int j = blockIdx.x * 4 + wave;
    const int idx = sidx[j];

    float2 v = reinterpret_cast<const float2*>(embed)[(size_t)idx * 64 + lane];
    float ss = v.x * v.x + v.y * v.y;
    ss += __shfl_xor(ss, 1);
    ss += __shfl_xor(ss, 2);
    ss += __shfl_xor(ss, 4);
    ss += __shfl_xor(ss, 8);
    ss += __shfl_xor(ss, 16);
    ss += __shfl_xor(ss, 32);
    const float rinv = 1.0f / fmaxf(sqrtf(ss), 1e-12f);
    en_bf[(size_t)j * 64 + lane] = pk2(v.x * rinv, v.y * rinv);
    if (lane == 0) {
        ln_samp[j] = logf(sprobs[idx] + 1e-10f);
        atomicOr(&bitmap[idx >> 5], 1u << (idx & 31));
    }
}

// ---------------- main: 256 rows x quarter of the negatives per block ----------------
__global__ __launch_bounds__(TPB, 4) void sspe_main(
    const float* __restrict__ hidden,
    const int* __restrict__ y,
    const float* __restrict__ embed,
    const float* __restrict__ sprobs,
    const float* __restrict__ ltemp,
    const unsigned int* __restrict__ en_bf,
    const float* __restrict__ ln_samp,
    float* __restrict__ pos_adj,   // [nrows]
    float* __restrict__ lsum,      // [NSPLIT][nrows]
    int nrows)
{
    const int t = threadIdx.x;
    const int wave = t >> 6;
    const int lane = t & 63;
    const int jh = blockIdx.x & 3;
    const int rb = (blockIdx.x >> 2) * RPB;

    __shared__ __align__(16) unsigned char smem[2 * 16384];   // B double buffer

    const float temp = __builtin_amdgcn_exp2f(fminf(ltemp[0], 4.6f) * L2E);
    const float t2 = temp * L2E;
    const float Mln = temp + 14.0f;   // uniform safe max (|cos|<=1, -log p <= 13.8)
    const float M2 = Mln * L2E;

    const int g = lane >> 4;     // column group
    const int rl = lane & 15;    // row within tile
    const int wbase = rb + wave * 64;

    // Fragment-order staging source offsets (proven R6): region d = nt*4+ks
    // holds at byte L*16 the B fragment lane L reads for (nt,ks).
    unsigned int soff[4];
    #pragma unroll
    for (int i = 0; i < 4; ++i) {
        const int d = wave * 4 + i;
        soff[i] = (unsigned int)((d >> 2) * 4096 + rl * 256 + (d & 3) * 64 + g * 16);
    }
    const unsigned char* en = reinterpret_cast<const unsigned char*>(en_bf)
                            + (size_t)jh * QSZ * 256;
    const int nb0 = jh * QSZ;

    // stage chunk 0 immediately; its latency hides under the prologue
    #pragma unroll
    for (int i = 0; i < 4; ++i)
        stage16(en + soff[i], smem + (wave * 4 + i) * 1024);

    // ---- Prologue: build A fragments straight from global (no LDS) ----
    bf16x8 A[4][4];
    #pragma unroll
    for (int tt = 0; tt < 4; ++tt) {
        const int row = wbase + tt * 16 + rl;
        const float* hp = hidden + (size_t)row * D + g * 8;
        float4 ha[4], hb[4];
        #pragma unroll
        for (int ks = 0; ks < 4; ++ks) {
            ha[ks] = *reinterpret_cast<const float4*>(hp + ks * 32);
            hb[ks] = *reinterpret_cast<const float4*>(hp + ks * 32 + 4);
        }
        float ss = 0.0f;
        #pragma unroll
        for (int ks = 0; ks < 4; ++ks) {
            ss += ha[ks].x * ha[ks].x + ha[ks].y * ha[ks].y
                + ha[ks].z * ha[ks].z + ha[ks].w * ha[ks].w
                + hb[ks].x * hb[ks].x + hb[ks].y * hb[ks].y
                + hb[ks].z * hb[ks].z + hb[ks].w * hb[ks].w;
        }
        ss += __shfl_xor(ss, 16);
        ss += __shfl_xor(ss, 32);
        const float rinv = 1.0f / fmaxf(sqrtf(ss), 1e-12f);
        #pragma unroll
        for (int ks = 0; ks < 4; ++ks) {
            union { bf16x8 v; unsigned int u[4]; } ua;
            ua.u[0] = pk2(ha[ks].x * rinv, ha[ks].y * rinv);
            ua.u[1] = pk2(ha[ks].z * rinv, ha[ks].w * rinv);
            ua.u[2] = pk2(hb[ks].x * rinv, hb[ks].y * rinv);
            ua.u[3] = pk2(hb[ks].z * rinv, hb[ks].w * rinv);
            A[tt][ks] = ua.v;
        }
        if (jh == 0) {
            const int yi = y[row];
            const float* ep = embed + (size_t)yi * D + g * 8;
            float dt = 0.0f, es = 0.0f;
            #pragma unroll
            for (int ks = 0; ks < 4; ++ks) {
                const float4 ea = *reinterpret_cast<const float4*>(ep + ks * 32);
                const float4 eb = *reinterpret_cast<const float4*>(ep + ks * 32 + 4);
                dt += ea.x * ha[ks].x + ea.y * ha[ks].y + ea.z * ha[ks].z + ea.w * ha[ks].w
                    + eb.x * hb[ks].x + eb.y * hb[ks].y + eb.z * hb[ks].z + eb.w * hb[ks].w;
                es += ea.x * ea.x + ea.y * ea.y + ea.z * ea.z + ea.w * ea.w
                    + eb.x * eb.x + eb.y * eb.y + eb.z * eb.z + eb.w * eb.w;
            }
            dt += __shfl_xor(dt, 16);  es += __shfl_xor(es, 16);
            dt += __shfl_xor(dt, 32);  es += __shfl_xor(es, 32);
            if (lane < 16)
                pos_adj[row] = dt * rinv * (1.0f / fmaxf(sqrtf(es), 1e-12f)) * temp
                               - logf(sprobs[yi] + 1e-10f);
        }
    }

    float l[4][4];
    #pragma unroll
    for (int tt = 0; tt < 4; ++tt)
        #pragma unroll
        for (int j = 0; j < 4; ++j) l[tt][j] = 0.0f;

    const int cj = rl;
    const int rgrp = g;

    // ---- Main loop: 8 chunks of 64 negs, double-buffered, 1 barrier/chunk ----
    #pragma unroll 1
    for (int ch = 0; ch < NCHQ; ++ch) {
        const int cur = (ch & 1) << 14;
        __syncthreads();   // chunk ch staged & visible

        float lk[4];
        #pragma unroll
        for (int nt = 0; nt < 4; ++nt)
            lk[nt] = ln_samp[nb0 + ch * 64 + nt * 16 + cj];

        if (ch + 1 < NCHQ) {
            const unsigned char* enn = en + (size_t)(ch + 1) * 16384;
            #pragma unroll
            for (int i = 0; i < 4; ++i)
                stage16(enn + soff[i], smem + (cur ^ 16384) + (wave * 4 + i) * 1024);
        }

        const unsigned char* bb = smem + cur + lane * 16;
        #pragma unroll
        for (int nt = 0; nt < 4; ++nt) {
            f32x4 c0 = {0.f, 0.f, 0.f, 0.f};
            f32x4 c1 = c0, c2 = c0, c3 = c0;
            #pragma unroll
            for (int ks = 0; ks < 4; ++ks) {
                const bf16x8 b = *reinterpret_cast<const bf16x8*>(bb + (nt * 4 + ks) * 1024);
                c0 = MFMA16(A[0][ks], b, c0, 0, 0, 0);
                c1 = MFMA16(A[1][ks], b, c1, 0, 0, 0);
                c2 = MFMA16(A[2][ks], b, c2, 0, 0, 0);
                c3 = MFMA16(A[3][ks], b, c3, 0, 0, 0);
            }
            const float nl2 = fmaf(lk[nt], -L2E, -M2);
            #pragma unroll
            for (int j = 0; j < 4; ++j) {
                l[0][j] += __builtin_amdgcn_exp2f(fmaf(c0[j], t2, nl2));
                l[1][j] += __builtin_amdgcn_exp2f(fmaf(c1[j], t2, nl2));
                l[2][j] += __builtin_amdgcn_exp2f(fmaf(c2[j], t2, nl2));
                l[3][j] += __builtin_amdgcn_exp2f(fmaf(c3[j], t2, nl2));
            }
        }
    }

    // ---- Reduce across the 16 neg-columns; store per-row partial sums ----
    #pragma unroll
    for (int tt = 0; tt < 4; ++tt)
        #pragma unroll
        for (int j = 0; j < 4; ++j) {
            float v = l[tt][j];
            v += __shfl_xor(v, 1);
            v += __shfl_xor(v, 2);
            v += __shfl_xor(v, 4);
            v += __shfl_xor(v, 8);
            l[tt][j] = v;
        }
    if (cj == 0) {
        float* dst = lsum + (size_t)jh * nrows + wbase;
        #pragma unroll
        for (int tt = 0; tt < 4; ++tt)
            #pragma unroll
            for (int j = 0; j < 4; ++j)
                dst[tt * 16 + rgrp * 4 + j] = l[tt][j];
    }
}

// ---------------- rows: combine splits, subtract collision terms, per-row loss ----------------
__global__ __launch_bounds__(TPB) void sspe_rows(
    const int* __restrict__ y,
    const float* __restrict__ ltemp,
    const int* __restrict__ sidx,
    const float* __restrict__ hidden,
    const unsigned int* __restrict__ en_bf,
    const float* __restrict__ ln_samp,
    const unsigned int* __restrict__ bitmap,
    const float* __restrict__ pos_adj,
    const float* __restrict__ lsum,
    int nrows,
    float2* __restrict__ partials)
{
    __shared__ int ssi[NNEG];
    __shared__ float2 red2[4];
    const int t = threadIdx.x;
    const int wave = t >> 6;
    const int lane = t & 63;
    const int r = blockIdx.x * TPB + t;

    for (int k = t; k < NNEG; k += TPB) ssi[k] = sidx[k];
    __syncthreads();

    const float temp = __builtin_amdgcn_exp2f(fminf(ltemp[0], 4.6f) * L2E);
    const float t2 = temp * L2E;
    const float Mln = temp + 14.0f;
    const float M2 = Mln * L2E;

    const int yr = y[r];
    float w = (yr != 0) ? 1.0f : 0.0f;
    float s = lsum[r] + lsum[(size_t)nrows + r]
            + lsum[2 * (size_t)nrows + r] + lsum[3 * (size_t)nrows + r];

    const bool hit = (w > 0.0f) && ((bitmap[yr >> 5] >> (yr & 31)) & 1u);
    unsigned long long m = __ballot(hit);
    while (m) {
        const int b = (int)(__ffsll((long long)m) - 1); m &= m - 1;
        const int yb = __shfl(yr, b);
        const int rB = __shfl(r, b);
        // normalized bf16-rounded hidden row rB (2 elems per lane)
        const float2 h2 = reinterpret_cast<const float2*>(hidden)[(size_t)rB * 64 + lane];
        float hs = h2.x * h2.x + h2.y * h2.y;
        #pragma unroll
        for (int k = 1; k <= 32; k <<= 1) hs += __shfl_xor(hs, k);
        const float rinv = 1.0f / fmaxf(sqrtf(hs), 1e-12f);
        const float hb0 = bfround(h2.x * rinv);
        const float hb1 = bfround(h2.y * rinv);
        float corr = 0.0f;
        for (int k = 0; k < NNEG; k += 64) {
            const int sj = ssi[k + lane];
            unsigned long long mm = __ballot(sj == yb);
            while (mm) {
                const int jj = (int)(__ffsll((long long)mm) - 1); mm &= mm - 1;
                const int j = k + jj;
                const unsigned int eu = en_bf[(size_t)j * 64 + lane];
                const float e0 = __uint_as_float(eu << 16);
                const float e1 = __uint_as_float(eu & 0xFFFF0000u);
                float d = hb0 * e0 + hb1 * e1;
                #pragma unroll
                for (int q = 1; q <= 32; q <<= 1) d += __shfl_xor(d, q);
                const float lkj = ln_samp[j];
                corr += __builtin_amdgcn_exp2f(fmaf(d, t2, fmaf(lkj, -L2E, -M2)));
            }
        }
        if (lane == b) s -= corr;
    }
    s = fmaxf(s, 0.0f);   // guard cancellation corner -> no NaN

    const float pa = pos_adj[r];
    const float stot = s + __builtin_amdgcn_exp2f(fmaf(pa, L2E, -M2));
    float per = (Mln + logf(stot) - pa) * w;

    #pragma unroll
    for (int msk = 1; msk < 64; msk <<= 1) {
        per += __shfl_xor(per, msk);
        w += __shfl_xor(w, msk);
    }
    if (lane == 0) red2[wave] = make_float2(per, w);
    __syncthreads();
    if (t == 0) {
        const float2 a = red2[0], b2 = red2[1], c = red2[2], d2 = red2[3];
        partials[blockIdx.x] = make_float2(a.x + b2.x + c.x + d2.x,
                                           a.y + b2.y + c.y + d2.y);
    }
}

// ---------------- finalize: deterministic reduction ----------------
__global__ __launch_bounds__(TPB) void sspe_finalize(
    const float2* __restrict__ partials, int n, float* __restrict__ out)
{
    __shared__ float ssum[TPB];
    __shared__ float scnt[TPB];
    const int t = threadIdx.x;
    float s = 0.0f, c = 0.0f;
    for (int i = t; i < n; i += TPB) {
        const float2 p = partials[i];
        s += p.x; c += p.y;
    }
    ssum[t] = s; scnt[t] = c;
    __syncthreads();
    for (int k = TPB / 2; k > 0; k >>= 1) {
        if (t < k) { ssum[t] += ssum[t + k]; scnt[t] += scnt[t + k]; }
        __syncthreads();
    }
    if (t == 0) out[0] = ssum[0] / fmaxf(scnt[0], 1.0f);
}

extern "C" void kernel_launch(void* const* d_in, const int* in_sizes, int n_in,
                              void* d_out, int out_size, void* d_ws, size_t ws_size,
                              hipStream_t stream) {
    const float* hidden = (const float*)d_in[0];
    const int*   yv     = (const int*)d_in[1];
    const float* embed  = (const float*)d_in[2];
    const float* sprobs = (const float*)d_in[3];
    const int*   sidx   = (const int*)d_in[4];
    const float* ltemp  = (const float*)d_in[5];
    float* out = (float*)d_out;

    const int nrows = in_sizes[1];                 // 65536
    const int vocab = in_sizes[3];                 // 100000
    const int bmw = (vocab + 31) / 32;
    const int nblocks = (nrows / RPB) * NSPLIT;    // 1024

    char* w = (char*)d_ws;
    size_t off = 0;
    unsigned int* en_bf = (unsigned int*)(w + off); off += (size_t)NNEG * D * 2;       // 512 KB
    float* ln_samp      = (float*)(w + off);        off += (size_t)NNEG * 4;           // 8 KB
    float* pos_adj      = (float*)(w + off);        off += (size_t)nrows * 4;          // 256 KB
    float* lsum         = (float*)(w + off);        off += (size_t)NSPLIT * nrows * 4; // 1 MB
    float2* partials    = (float2*)(w + off);       off += (size_t)(nrows / TPB) * 8;  // 2 KB
    unsigned int* bitmap = (unsigned int*)(w + off);

    sspe_clear<<<(bmw + TPB - 1) / TPB, TPB, 0, stream>>>(bitmap, bmw);
    sspe_prep<<<NNEG / 4, TPB, 0, stream>>>(embed, sprobs, sidx, en_bf, ln_samp, bitmap);
    sspe_main<<<nblocks, TPB, 0, stream>>>(hidden, yv, embed, sprobs, ltemp,
                                           en_bf, ln_samp, pos_adj, lsum, nrows);
    sspe_rows<<<nrows / TPB, TPB, 0, stream>>>(yv, ltemp, sidx, hidden, en_bf, ln_samp,
                                               bitmap, pos_adj, lsum, nrows, partials);
    sspe_finalize<<<1, TPB, 0, stream>>>(partials, nrows / TPB, out);
}

// Round 9
// 114.883 us; speedup vs baseline: 1.5630x; 1.5630x over previous
//
#include <hip/hip_runtime.h>
#include <math.h>

#define TPB 256
#define NNEG 2048
#define D 128
#define RPB 64               // rows per block (4 waves x 16)
#define NSPLIT 2             // negative-range splits
#define HALF (NNEG / NSPLIT) // 1024 negs per block
#define CHUNK 32             // negs per staged chunk (8 KB)
#define NCHQ (HALF / CHUNK)  // 32 chunks
#define L2E 1.44269504088896340736f

typedef __attribute__((ext_vector_type(8))) short bf16x8;
typedef __attribute__((ext_vector_type(4))) float f32x4;

#define MFMA16 __builtin_amdgcn_mfma_f32_16x16x32_bf16

static __device__ __forceinline__ unsigned int f2bf(float f) {
    unsigned int u = __float_as_uint(f);
    return (u + 0x7FFFu + ((u >> 16) & 1u)) >> 16;
}
static __device__ __forceinline__ float bfround(float f) {
    unsigned int u = __float_as_uint(f);
    return __uint_as_float((u + 0x7FFFu + ((u >> 16) & 1u)) & 0xFFFF0000u);
}
static __device__ __forceinline__ unsigned int pk2(float x, float y) {
    return f2bf(x) | (f2bf(y) << 16);
}

static __device__ __forceinline__ void stage16(const void* g, void* l) {
    __builtin_amdgcn_global_load_lds(
        (const __attribute__((address_space(1))) unsigned int*)g,
        (__attribute__((address_space(3))) unsigned int*)l, 16, 0, 0);
}

// ---------------- clear: zero the vocab bitmap ----------------
__global__ __launch_bounds__(TPB) void sspe_clear(unsigned int* __restrict__ bm, int words) {
    const int i = blockIdx.x * TPB + threadIdx.x;
    if (i < words) bm[i] = 0u;
}

// ---------------- prep: normalize negatives -> bf16, log(samp_p), bitmap ----------------
__global__ __launch_bounds__(TPB) void sspe_prep(
    const float* __restrict__ embed,
    const float* __restrict__ sprobs,
    const int* __restrict__ sidx,
    unsigned int* __restrict__ en_bf,
    float* __restrict__ ln_samp,
    unsigned int* __restrict__ bitmap)
{
    const int t = threadIdx.x;
    const int wave = t >> 6;
    const int lane = t & 63;
    const int j = blockIdx.x * 4 + wave;
    const int idx = sidx[j];

    float2 v = reinterpret_cast<const float2*>(embed)[(size_t)idx * 64 + lane];
    float ss = v.x * v.x + v.y * v.y;
    ss += __shfl_xor(ss, 1);
    ss += __shfl_xor(ss, 2);
    ss += __shfl_xor(ss, 4);
    ss += __shfl_xor(ss, 8);
    ss += __shfl_xor(ss, 16);
    ss += __shfl_xor(ss, 32);
    const float rinv = 1.0f / fmaxf(sqrtf(ss), 1e-12f);
    en_bf[(size_t)j * 64 + lane] = pk2(v.x * rinv, v.y * rinv);
    if (lane == 0) {
        ln_samp[j] = logf(sprobs[idx] + 1e-10f);
        atomicOr(&bitmap[idx >> 5], 1u << (idx & 31));
    }
}

// ---------------- main: 64 rows x half the negatives per block ----------------
__global__ __launch_bounds__(TPB, 8) void sspe_main(
    const float* __restrict__ hidden,
    const int* __restrict__ y,
    const float* __restrict__ embed,
    const float* __restrict__ sprobs,
    const float* __restrict__ ltemp,
    const unsigned int* __restrict__ en_bf,
    const float* __restrict__ ln_samp,
    float* __restrict__ pos_adj,   // [nrows]
    float* __restrict__ lsum,      // [NSPLIT][nrows]
    int nrows)
{
    const int t = threadIdx.x;
    const int wave = t >> 6;
    const int lane = t & 63;

    // XCD-aware swizzle: consecutive work ids (the two jh halves of a row
    // group) land on the SAME XCD's L2 -> hidden fetched once per XCD.
    const int bid = (int)blockIdx.x;
    const int wg = (bid & 7) * ((int)gridDim.x >> 3) + (bid >> 3);
    const int jh = wg & 1;
    const int rb = (wg >> 1) * RPB;

    // 16 KB: prologue hidden tile (64 rows x 256B) == two 8 KB B buffers later
    __shared__ __align__(16) unsigned char smem[2 * 8192];

    const float temp = __builtin_amdgcn_exp2f(fminf(ltemp[0], 4.6f) * L2E);
    const float t2 = temp * L2E;
    const float Mln = temp + 14.0f;   // uniform safe max (|cos|<=1, -log p <= 13.8)
    const float M2 = Mln * L2E;

    const int g = lane >> 4;     // column group
    const int rl = lane & 15;    // row/neg within tile

    // ---- Prologue: normalize 16 rows/wave -> bf16 into smem (swizzled rows) ----
    if (jh == 0) {
        #pragma unroll 1
        for (int i = 0; i < 16; i += 4) {
            float2 h2[4], e2[4];
            int yi[4];
            #pragma unroll
            for (int u = 0; u < 4; ++u) {
                const int lr = wave * 16 + i + u;
                h2[u] = reinterpret_cast<const float2*>(hidden)[(size_t)(rb + lr) * 64 + lane];
                yi[u] = y[rb + lr];
            }
            #pragma unroll
            for (int u = 0; u < 4; ++u)
                e2[u] = reinterpret_cast<const float2*>(embed)[(size_t)yi[u] * 64 + lane];
            float ss[4], es[4], dt[4];
            #pragma unroll
            for (int u = 0; u < 4; ++u) {
                ss[u] = h2[u].x * h2[u].x + h2[u].y * h2[u].y;
                es[u] = e2[u].x * e2[u].x + e2[u].y * e2[u].y;
                dt[u] = h2[u].x * e2[u].x + h2[u].y * e2[u].y;
            }
            #pragma unroll
            for (int m = 1; m <= 32; m <<= 1)
                #pragma unroll
                for (int u = 0; u < 4; ++u) {
                    ss[u] += __shfl_xor(ss[u], m);
                    es[u] += __shfl_xor(es[u], m);
                    dt[u] += __shfl_xor(dt[u], m);
                }
            #pragma unroll
            for (int u = 0; u < 4; ++u) {
                const int lr = wave * 16 + i + u;
                const float rinv = 1.0f / fmaxf(sqrtf(ss[u]), 1e-12f);
                *reinterpret_cast<unsigned int*>(
                    smem + lr * 256 + ((lane * 4) ^ ((lr & 7) << 4)))
                    = pk2(h2[u].x * rinv, h2[u].y * rinv);
                if (lane == 0)
                    pos_adj[rb + lr] = dt[u] * rinv * (1.0f / fmaxf(sqrtf(es[u]), 1e-12f)) * temp
                                       - logf(sprobs[yi[u]] + 1e-10f);
            }
        }
    } else {
        #pragma unroll 1
        for (int i = 0; i < 16; i += 4) {
            float2 h2[4];
            #pragma unroll
            for (int u = 0; u < 4; ++u) {
                const int lr = wave * 16 + i + u;
                h2[u] = reinterpret_cast<const float2*>(hidden)[(size_t)(rb + lr) * 64 + lane];
            }
            float ss[4];
            #pragma unroll
            for (int u = 0; u < 4; ++u)
                ss[u] = h2[u].x * h2[u].x + h2[u].y * h2[u].y;
            #pragma unroll
            for (int m = 1; m <= 32; m <<= 1)
                #pragma unroll
                for (int u = 0; u < 4; ++u)
                    ss[u] += __shfl_xor(ss[u], m);
            #pragma unroll
            for (int u = 0; u < 4; ++u) {
                const int lr = wave * 16 + i + u;
                const float rinv = 1.0f / fmaxf(sqrtf(ss[u]), 1e-12f);
                *reinterpret_cast<unsigned int*>(
                    smem + lr * 256 + ((lane * 4) ^ ((lr & 7) << 4)))
                    = pk2(h2[u].x * rinv, h2[u].y * rinv);
            }
        }
    }
    __syncthreads();

    // ---- A fragments: one 16-row tile per wave ----
    bf16x8 A[4];
    {
        const int row = wave * 16 + rl;
        const int rx = (lane & 7) << 4;
        #pragma unroll
        for (int ks = 0; ks < 4; ++ks)
            A[ks] = *reinterpret_cast<const bf16x8*>(
                smem + row * 256 + ((ks * 64 + (g << 4)) ^ rx));
    }
    __syncthreads();   // all A reads done before restaging over smem

    // Fragment-order staging (proven R6): region d = nt*4+ks holds at byte
    // L*16 exactly the B fragment lane L consumes for (nt,ks). Per-lane
    // GLOBAL source carries the permutation; LDS dest stays linear.
    unsigned int soff[2];
    #pragma unroll
    for (int i = 0; i < 2; ++i) {
        const int d = wave * 2 + i;
        soff[i] = (unsigned int)((d >> 2) * 4096 + rl * 256 + (d & 3) * 64 + g * 16);
    }
    const unsigned char* en = reinterpret_cast<const unsigned char*>(en_bf)
                            + (size_t)jh * HALF * 256;
    const int nb0 = jh * HALF;

    // stage chunk 0 -> buffer 0
    #pragma unroll
    for (int i = 0; i < 2; ++i)
        stage16(en + soff[i], smem + (wave * 2 + i) * 1024);

    float l[4];
    l[0] = l[1] = l[2] = l[3] = 0.0f;

    // ---- Main loop: 32 chunks of 32 negs, double-buffered, 1 barrier/chunk ----
    #pragma unroll 1
    for (int ch = 0; ch < NCHQ; ++ch) {
        const int cur = (ch & 1) << 13;
        __syncthreads();   // chunk ch staged & visible

        const float lk0 = ln_samp[nb0 + ch * 32 + rl];
        const float lk1 = ln_samp[nb0 + ch * 32 + 16 + rl];

        if (ch + 1 < NCHQ) {
            const unsigned char* enn = en + (size_t)(ch + 1) * 8192;
            #pragma unroll
            for (int i = 0; i < 2; ++i)
                stage16(enn + soff[i], smem + (cur ^ 8192) + (wave * 2 + i) * 1024);
        }

        const unsigned char* bb = smem + cur + lane * 16;
        f32x4 c0 = {0.f, 0.f, 0.f, 0.f};
        f32x4 c1 = {0.f, 0.f, 0.f, 0.f};
        #pragma unroll
        for (int ks = 0; ks < 4; ++ks) {
            const bf16x8 b0 = *reinterpret_cast<const bf16x8*>(bb + ks * 1024);
            const bf16x8 b1 = *reinterpret_cast<const bf16x8*>(bb + (4 + ks) * 1024);
            c0 = MFMA16(A[ks], b0, c0, 0, 0, 0);
            c1 = MFMA16(A[ks], b1, c1, 0, 0, 0);
        }
        const float nl0 = fmaf(lk0, -L2E, -M2);
        const float nl1 = fmaf(lk1, -L2E, -M2);
        #pragma unroll
        for (int j = 0; j < 4; ++j) {
            l[j] += __builtin_amdgcn_exp2f(fmaf(c0[j], t2, nl0));
            l[j] += __builtin_amdgcn_exp2f(fmaf(c1[j], t2, nl1));
        }
    }

    // ---- Reduce across the 16 neg-columns; store per-row partial sums ----
    #pragma unroll
    for (int j = 0; j < 4; ++j) {
        float v = l[j];
        v += __shfl_xor(v, 1);
        v += __shfl_xor(v, 2);
        v += __shfl_xor(v, 4);
        v += __shfl_xor(v, 8);
        l[j] = v;
    }
    if (rl == 0) {
        float* dst = lsum + (size_t)jh * nrows + rb + wave * 16 + g * 4;
        #pragma unroll
        for (int j = 0; j < 4; ++j) dst[j] = l[j];
    }
}

// ---------------- rows: combine splits, subtract collision terms, per-row loss ----------------
__global__ __launch_bounds__(TPB) void sspe_rows(
    const int* __restrict__ y,
    const float* __restrict__ ltemp,
    const int* __restrict__ sidx,
    const float* __restrict__ hidden,
    const unsigned int* __restrict__ en_bf,
    const float* __restrict__ ln_samp,
    const unsigned int* __restrict__ bitmap,
    const float* __restrict__ pos_adj,
    const float* __restrict__ lsum,
    int nrows,
    float2* __restrict__ partials)
{
    __shared__ int ssi[NNEG];
    __shared__ float2 red2[4];
    const int t = threadIdx.x;
    const int wave = t >> 6;
    const int lane = t & 63;
    const int r = blockIdx.x * TPB + t;

    for (int k = t; k < NNEG; k += TPB) ssi[k] = sidx[k];
    __syncthreads();

    const float temp = __builtin_amdgcn_exp2f(fminf(ltemp[0], 4.6f) * L2E);
    const float t2 = temp * L2E;
    const float Mln = temp + 14.0f;
    const float M2 = Mln * L2E;

    const int yr = y[r];
    float w = (yr != 0) ? 1.0f : 0.0f;
    float s = lsum[r] + lsum[(size_t)nrows + r];

    const bool hit = (w > 0.0f) && ((bitmap[yr >> 5] >> (yr & 31)) & 1u);
    unsigned long long m = __ballot(hit);
    while (m) {
        const int b = (int)(__ffsll((long long)m) - 1); m &= m - 1;
        const int yb = __shfl(yr, b);
        const int rB = __shfl(r, b);
        const float2 h2 = reinterpret_cast<const float2*>(hidden)[(size_t)rB * 64 + lane];
        float hs = h2.x * h2.x + h2.y * h2.y;
        #pragma unroll
        for (int k = 1; k <= 32; k <<= 1) hs += __shfl_xor(hs, k);
        const float rinv = 1.0f / fmaxf(sqrtf(hs), 1e-12f);
        const float hb0 = bfround(h2.x * rinv);
        const float hb1 = bfround(h2.y * rinv);
        float corr = 0.0f;
        for (int k = 0; k < NNEG; k += 64) {
            const int sj = ssi[k + lane];
            unsigned long long mm = __ballot(sj == yb);
            while (mm) {
                const int jj = (int)(__ffsll((long long)mm) - 1); mm &= mm - 1;
                const int j = k + jj;
                const unsigned int eu = en_bf[(size_t)j * 64 + lane];
                const float e0 = __uint_as_float(eu << 16);
                const float e1 = __uint_as_float(eu & 0xFFFF0000u);
                float d = hb0 * e0 + hb1 * e1;
                #pragma unroll
                for (int q = 1; q <= 32; q <<= 1) d += __shfl_xor(d, q);
                corr += __builtin_amdgcn_exp2f(fmaf(d, t2, fmaf(ln_samp[j], -L2E, -M2)));
            }
        }
        if (lane == b) s -= corr;
    }
    s = fmaxf(s, 0.0f);   // guard cancellation corner

    const float pa = pos_adj[r];
    const float stot = s + __builtin_amdgcn_exp2f(fmaf(pa, L2E, -M2));
    float per = (Mln + logf(stot) - pa) * w;

    #pragma unroll
    for (int msk = 1; msk < 64; msk <<= 1) {
        per += __shfl_xor(per, msk);
        w += __shfl_xor(w, msk);
    }
    if (lane == 0) red2[wave] = make_float2(per, w);
    __syncthreads();
    if (t == 0) {
        const float2 a = red2[0], b2 = red2[1], c = red2[2], d2 = red2[3];
        partials[blockIdx.x] = make_float2(a.x + b2.x + c.x + d2.x,
                                           a.y + b2.y + c.y + d2.y);
    }
}

// ---------------- finalize: deterministic reduction ----------------
__global__ __launch_bounds__(TPB) void sspe_finalize(
    const float2* __restrict__ partials, int n, float* __restrict__ out)
{
    __shared__ float ssum[TPB];
    __shared__ float scnt[TPB];
    const int t = threadIdx.x;
    float s = 0.0f, c = 0.0f;
    for (int i = t; i < n; i += TPB) {
        const float2 p = partials[i];
        s += p.x; c += p.y;
    }
    ssum[t] = s; scnt[t] = c;
    __syncthreads();
    for (int k = TPB / 2; k > 0; k >>= 1) {
        if (t < k) { ssum[t] += ssum[t + k]; scnt[t] += scnt[t + k]; }
        __syncthreads();
    }
    if (t == 0) out[0] = ssum[0] / fmaxf(scnt[0], 1.0f);
}

extern "C" void kernel_launch(void* const* d_in, const int* in_sizes, int n_in,
                              void* d_out, int out_size, void* d_ws, size_t ws_size,
                              hipStream_t stream) {
    const float* hidden = (const float*)d_in[0];
    const int*   yv     = (const int*)d_in[1];
    const float* embed  = (const float*)d_in[2];
    const float* sprobs = (const float*)d_in[3];
    const int*   sidx   = (const int*)d_in[4];
    const float* ltemp  = (const float*)d_in[5];
    float* out = (float*)d_out;

    const int nrows = in_sizes[1];                 // 65536
    const int vocab = in_sizes[3];                 // 100000
    const int bmw = (vocab + 31) / 32;
    const int nblocks = (nrows / RPB) * NSPLIT;    // 2048

    char* w = (char*)d_ws;
    size_t off = 0;
    unsigned int* en_bf = (unsigned int*)(w + off); off += (size_t)NNEG * D * 2;       // 512 KB
    float* ln_samp      = (float*)(w + off);        off += (size_t)NNEG * 4;           // 8 KB
    float* pos_adj      = (float*)(w + off);        off += (size_t)nrows * 4;          // 256 KB
    float* lsum         = (float*)(w + off);        off += (size_t)NSPLIT * nrows * 4; // 512 KB
    float2* partials    = (float2*)(w + off);       off += (size_t)(nrows / TPB) * 8;  // 2 KB
    unsigned int* bitmap = (unsigned int*)(w + off);

    sspe_clear<<<(bmw + TPB - 1) / TPB, TPB, 0, stream>>>(bitmap, bmw);
    sspe_prep<<<NNEG / 4, TPB, 0, stream>>>(embed, sprobs, sidx, en_bf, ln_samp, bitmap);
    sspe_main<<<nblocks, TPB, 0, stream>>>(hidden, yv, embed, sprobs, ltemp,
                                           en_bf, ln_samp, pos_adj, lsum, nrows);
    sspe_rows<<<nrows / TPB, TPB, 0, stream>>>(yv, ltemp, sidx, hidden, en_bf, ln_samp,
                                               bitmap, pos_adj, lsum, nrows, partials);
    sspe_finalize<<<1, TPB, 0, stream>>>(partials, nrows / TPB, out);
}

// Round 10
// 104.776 us; speedup vs baseline: 1.7137x; 1.0965x over previous
//
#include <hip/hip_runtime.h>
#include <math.h>

#define TPB 256
#define NNEG 2048
#define D 128
#define RPB 128              // rows per block (4 waves x 32)
#define NSPLIT 2             // negative-range splits
#define HALF (NNEG / NSPLIT) // 1024 negs per block
#define CHUNK 32             // negs per staged chunk (8 KB)
#define NCHQ (HALF / CHUNK)  // 32 chunks
#define L2E 1.44269504088896340736f

typedef __attribute__((ext_vector_type(8))) short bf16x8;
typedef __attribute__((ext_vector_type(4))) float f32x4;

#define MFMA16 __builtin_amdgcn_mfma_f32_16x16x32_bf16

static __device__ __forceinline__ unsigned int f2bf(float f) {
    unsigned int u = __float_as_uint(f);
    return (u + 0x7FFFu + ((u >> 16) & 1u)) >> 16;
}
static __device__ __forceinline__ float bfround(float f) {
    unsigned int u = __float_as_uint(f);
    return __uint_as_float((u + 0x7FFFu + ((u >> 16) & 1u)) & 0xFFFF0000u);
}
static __device__ __forceinline__ unsigned int pk2(float x, float y) {
    return f2bf(x) | (f2bf(y) << 16);
}

static __device__ __forceinline__ void stage16(const void* g, void* l) {
    __builtin_amdgcn_global_load_lds(
        (const __attribute__((address_space(1))) unsigned int*)g,
        (__attribute__((address_space(3))) unsigned int*)l, 16, 0, 0);
}

// ---------------- clear: zero the vocab bitmap ----------------
__global__ __launch_bounds__(TPB) void sspe_clear(unsigned int* __restrict__ bm, int words) {
    const int i = blockIdx.x * TPB + threadIdx.x;
    if (i < words) bm[i] = 0u;
}

// ---------------- prep: normalize negatives -> bf16, log(samp_p), bitmap ----------------
__global__ __launch_bounds__(TPB) void sspe_prep(
    const float* __restrict__ embed,
    const float* __restrict__ sprobs,
    const int* __restrict__ sidx,
    unsigned int* __restrict__ en_bf,
    float* __restrict__ ln_samp,
    unsigned int* __restrict__ bitmap)
{
    const int t = threadIdx.x;
    const int wave = t >> 6;
    const int lane = t & 63;
    const int j = blockIdx.x * 4 + wave;
    const int idx = sidx[j];

    float2 v = reinterpret_cast<const float2*>(embed)[(size_t)idx * 64 + lane];
    float ss = v.x * v.x + v.y * v.y;
    ss += __shfl_xor(ss, 1);
    ss += __shfl_xor(ss, 2);
    ss += __shfl_xor(ss, 4);
    ss += __shfl_xor(ss, 8);
    ss += __shfl_xor(ss, 16);
    ss += __shfl_xor(ss, 32);
    const float rinv = 1.0f / fmaxf(sqrtf(ss), 1e-12f);
    en_bf[(size_t)j * 64 + lane] = pk2(v.x * rinv, v.y * rinv);
    if (lane == 0) {
        ln_samp[j] = logf(sprobs[idx] + 1e-10f);
        atomicOr(&bitmap[idx >> 5], 1u << (idx & 31));
    }
}

// ---------------- main: 128 rows x half the negatives per block ----------------
__global__ __launch_bounds__(TPB, 4) void sspe_main(
    const float* __restrict__ hidden,
    const int* __restrict__ y,
    const float* __restrict__ embed,
    const float* __restrict__ sprobs,
    const float* __restrict__ ltemp,
    const unsigned int* __restrict__ en_bf,
    const float* __restrict__ ln_samp,
    float* __restrict__ pos_adj,   // [nrows]
    float* __restrict__ lsum,      // [NSPLIT][nrows]
    int nrows)
{
    const int t = threadIdx.x;
    const int wave = t >> 6;
    const int lane = t & 63;

    // XCD-aware swizzle (grid 1024, %8==0 -> bijective)
    const int bid = (int)blockIdx.x;
    const int wg = (bid & 7) * ((int)gridDim.x >> 3) + (bid >> 3);
    const int jh = wg & 1;
    const int rb = (wg >> 1) * RPB;

    // 32 KB tile for prologue (128 rows x 256B); first 24 KB reused as
    // THREE 8 KB B-buffers (depth-2 counted-vmcnt pipeline).
    __shared__ __align__(16) unsigned char smem[RPB * 256];
    __shared__ float lk_lds[HALF];   // 4 KB: ln_samp slice, so main loop has NO global loads

    const float temp = __builtin_amdgcn_exp2f(fminf(ltemp[0], 4.6f) * L2E);
    const float t2 = temp * L2E;
    const float Mln = temp + 14.0f;   // uniform safe max (|cos|<=1, -log p <= 13.8)
    const float M2 = Mln * L2E;

    const int g = lane >> 4;     // column group
    const int rl = lane & 15;    // row/neg within tile
    const int nb0 = jh * HALF;

    // ---- Prologue: normalize 32 rows/wave -> bf16 into smem (swizzled rows) ----
    #pragma unroll 1
    for (int i = 0; i < 32; i += 4) {
        float2 h2[4], e2[4];
        int yi[4];
        #pragma unroll
        for (int u = 0; u < 4; ++u) {
            const int lr = wave * 32 + i + u;
            h2[u] = reinterpret_cast<const float2*>(hidden)[(size_t)(rb + lr) * 64 + lane];
            yi[u] = y[rb + lr];
        }
        if (jh == 0) {
            #pragma unroll
            for (int u = 0; u < 4; ++u)
                e2[u] = reinterpret_cast<const float2*>(embed)[(size_t)yi[u] * 64 + lane];
        } else {
            #pragma unroll
            for (int u = 0; u < 4; ++u) e2[u] = make_float2(0.0f, 0.0f);
        }
        float ss[4], es[4], dt[4];
        #pragma unroll
        for (int u = 0; u < 4; ++u) {
            ss[u] = h2[u].x * h2[u].x + h2[u].y * h2[u].y;
            es[u] = e2[u].x * e2[u].x + e2[u].y * e2[u].y;
            dt[u] = h2[u].x * e2[u].x + h2[u].y * e2[u].y;
        }
        #pragma unroll
        for (int m = 1; m <= 32; m <<= 1)
            #pragma unroll
            for (int u = 0; u < 4; ++u) {
                ss[u] += __shfl_xor(ss[u], m);
                es[u] += __shfl_xor(es[u], m);
                dt[u] += __shfl_xor(dt[u], m);
            }
        #pragma unroll
        for (int u = 0; u < 4; ++u) {
            const int lr = wave * 32 + i + u;
            const float rinv = 1.0f / fmaxf(sqrtf(ss[u]), 1e-12f);
            *reinterpret_cast<unsigned int*>(
                smem + lr * 256 + ((lane * 4) ^ ((lr & 7) << 4)))
                = pk2(h2[u].x * rinv, h2[u].y * rinv);
            if (jh == 0 && lane == 0)
                pos_adj[rb + lr] = dt[u] * rinv * (1.0f / fmaxf(sqrtf(es[u]), 1e-12f)) * temp
                                   - logf(sprobs[yi[u]] + 1e-10f);
        }
    }
    for (int k = t; k < HALF; k += TPB) lk_lds[k] = ln_samp[nb0 + k];
    __syncthreads();

    // ---- A fragments: two 16-row tiles per wave ----
    bf16x8 A0[4], A1[4];
    {
        const int row0 = wave * 32 + rl;
        const int rx = (rl & 7) << 4;
        #pragma unroll
        for (int ks = 0; ks < 4; ++ks) {
            const int col = (ks * 64 + (g << 4)) ^ rx;
            A0[ks] = *reinterpret_cast<const bf16x8*>(smem + row0 * 256 + col);
            A1[ks] = *reinterpret_cast<const bf16x8*>(smem + (row0 + 16) * 256 + col);
        }
    }
    __syncthreads();   // all A reads + lk_lds fills complete before restaging

    // Fragment-order staging (proven R6): region d = nt*4+ks holds at byte
    // L*16 exactly the B fragment lane L consumes. Per-lane GLOBAL source
    // carries the permutation; LDS dest stays linear. Wave stages d=2w,2w+1.
    unsigned int soff[2];
    #pragma unroll
    for (int i = 0; i < 2; ++i) {
        const int d = wave * 2 + i;
        soff[i] = (unsigned int)(((d >> 2) * 16 + rl) * 256 + (d & 3) * 64 + g * 16);
    }
    const unsigned char* en = reinterpret_cast<const unsigned char*>(en_bf)
                            + (size_t)nb0 * 256;

    // stage chunks 0 and 1 (2 stage16 per wave each; 4 outstanding)
    stage16(en + soff[0], smem + (wave * 2 + 0) * 1024);
    stage16(en + soff[1], smem + (wave * 2 + 1) * 1024);
    stage16(en + 8192 + soff[0], smem + 8192 + (wave * 2 + 0) * 1024);
    stage16(en + 8192 + soff[1], smem + 8192 + (wave * 2 + 1) * 1024);

    float l0[4] = {0.f, 0.f, 0.f, 0.f};
    float l1[4] = {0.f, 0.f, 0.f, 0.f};
    int bcur = 0, bstg = 2;   // ch%3 and (ch+2)%3

    // ---- Main loop: counted vmcnt(2) -- stages stay in flight across
    // barriers; never drained to 0 until the peeled tail. ----
    #pragma unroll 1
    for (int ch = 0; ch < NCHQ - 1; ++ch) {
        // stage(ch) done (oldest 2 of 4 outstanding); all waves synced.
        asm volatile("s_waitcnt vmcnt(2)\n\ts_barrier" ::: "memory");

        if (ch + 2 < NCHQ) {   // safe: barrier above proved all waves done READING buf bstg
            const unsigned char* enn = en + (size_t)(ch + 2) * 8192;
            stage16(enn + soff[0], smem + bstg * 8192 + (wave * 2 + 0) * 1024);
            stage16(enn + soff[1], smem + bstg * 8192 + (wave * 2 + 1) * 1024);
        }

        const float lk0 = lk_lds[ch * 32 + rl];
        const float lk1 = lk_lds[ch * 32 + 16 + rl];
        const unsigned char* bb = smem + bcur * 8192 + lane * 16;

        f32x4 c00 = {0.f, 0.f, 0.f, 0.f}, c01 = c00, c10 = c00, c11 = c00;
        #pragma unroll
        for (int ks = 0; ks < 4; ++ks) {
            const bf16x8 b0 = *reinterpret_cast<const bf16x8*>(bb + ks * 1024);
            const bf16x8 b1 = *reinterpret_cast<const bf16x8*>(bb + (4 + ks) * 1024);
            c00 = MFMA16(A0[ks], b0, c00, 0, 0, 0);
            c01 = MFMA16(A1[ks], b0, c01, 0, 0, 0);
            c10 = MFMA16(A0[ks], b1, c10, 0, 0, 0);
            c11 = MFMA16(A1[ks], b1, c11, 0, 0, 0);
        }
        const float nl0 = fmaf(lk0, -L2E, -M2);
        const float nl1 = fmaf(lk1, -L2E, -M2);
        #pragma unroll
        for (int j = 0; j < 4; ++j) {
            l0[j] += __builtin_amdgcn_exp2f(fmaf(c00[j], t2, nl0));
            l1[j] += __builtin_amdgcn_exp2f(fmaf(c01[j], t2, nl0));
            l0[j] += __builtin_amdgcn_exp2f(fmaf(c10[j], t2, nl1));
            l1[j] += __builtin_amdgcn_exp2f(fmaf(c11[j], t2, nl1));
        }
        bcur = (bcur == 2) ? 0 : bcur + 1;
        bstg = (bstg == 2) ? 0 : bstg + 1;
    }
    // ---- peeled tail chunk (only place vmcnt drains to 0) ----
    {
        const int ch = NCHQ - 1;
        asm volatile("s_waitcnt vmcnt(0)\n\ts_barrier" ::: "memory");
        const float lk0 = lk_lds[ch * 32 + rl];
        const float lk1 = lk_lds[ch * 32 + 16 + rl];
        const unsigned char* bb = smem + bcur * 8192 + lane * 16;
        f32x4 c00 = {0.f, 0.f, 0.f, 0.f}, c01 = c00, c10 = c00, c11 = c00;
        #pragma unroll
        for (int ks = 0; ks < 4; ++ks) {
            const bf16x8 b0 = *reinterpret_cast<const bf16x8*>(bb + ks * 1024);
            const bf16x8 b1 = *reinterpret_cast<const bf16x8*>(bb + (4 + ks) * 1024);
            c00 = MFMA16(A0[ks], b0, c00, 0, 0, 0);
            c01 = MFMA16(A1[ks], b0, c01, 0, 0, 0);
            c10 = MFMA16(A0[ks], b1, c10, 0, 0, 0);
            c11 = MFMA16(A1[ks], b1, c11, 0, 0, 0);
        }
        const float nl0 = fmaf(lk0, -L2E, -M2);
        const float nl1 = fmaf(lk1, -L2E, -M2);
        #pragma unroll
        for (int j = 0; j < 4; ++j) {
            l0[j] += __builtin_amdgcn_exp2f(fmaf(c00[j], t2, nl0));
            l1[j] += __builtin_amdgcn_exp2f(fmaf(c01[j], t2, nl0));
            l0[j] += __builtin_amdgcn_exp2f(fmaf(c10[j], t2, nl1));
            l1[j] += __builtin_amdgcn_exp2f(fmaf(c11[j], t2, nl1));
        }
    }

    // ---- Reduce across the 16 neg-columns; store per-row partial sums ----
    #pragma unroll
    for (int j = 0; j < 4; ++j) {
        float v0 = l0[j], v1 = l1[j];
        v0 += __shfl_xor(v0, 1);  v1 += __shfl_xor(v1, 1);
        v0 += __shfl_xor(v0, 2);  v1 += __shfl_xor(v1, 2);
        v0 += __shfl_xor(v0, 4);  v1 += __shfl_xor(v1, 4);
        v0 += __shfl_xor(v0, 8);  v1 += __shfl_xor(v1, 8);
        l0[j] = v0;
        l1[j] = v1;
    }
    if (rl == 0) {
        float* dst = lsum + (size_t)jh * nrows + rb + wave * 32 + g * 4;
        #pragma unroll
        for (int j = 0; j < 4; ++j) {
            dst[j] = l0[j];
            dst[16 + j] = l1[j];
        }
    }
}

// ---------------- rows: combine splits, subtract collision terms, per-row loss ----------------
__global__ __launch_bounds__(TPB) void sspe_rows(
    const int* __restrict__ y,
    const float* __restrict__ ltemp,
    const int* __restrict__ sidx,
    const float* __restrict__ hidden,
    const unsigned int* __restrict__ en_bf,
    const float* __restrict__ ln_samp,
    const unsigned int* __restrict__ bitmap,
    const float* __restrict__ pos_adj,
    const float* __restrict__ lsum,
    int nrows,
    float2* __restrict__ partials)
{
    __shared__ int ssi[NNEG];
    __shared__ float2 red2[4];
    const int t = threadIdx.x;
    const int wave = t >> 6;
    const int lane = t & 63;
    const int r = blockIdx.x * TPB + t;

    for (int k = t; k < NNEG; k += TPB) ssi[k] = sidx[k];
    __syncthreads();

    const float temp = __builtin_amdgcn_exp2f(fminf(ltemp[0], 4.6f) * L2E);
    const float t2 = temp * L2E;
    const float Mln = temp + 14.0f;
    const float M2 = Mln * L2E;

    const int yr = y[r];
    float w = (yr != 0) ? 1.0f : 0.0f;
    float s = lsum[r] + lsum[(size_t)nrows + r];

    const bool hit = (w > 0.0f) && ((bitmap[yr >> 5] >> (yr & 31)) & 1u);
    unsigned long long m = __ballot(hit);
    while (m) {
        const int b = (int)(__ffsll((long long)m) - 1); m &= m - 1;
        const int yb = __shfl(yr, b);
        const int rB = __shfl(r, b);
        const float2 h2 = reinterpret_cast<const float2*>(hidden)[(size_t)rB * 64 + lane];
        float hs = h2.x * h2.x + h2.y * h2.y;
        #pragma unroll
        for (int k = 1; k <= 32; k <<= 1) hs += __shfl_xor(hs, k);
        const float rinv = 1.0f / fmaxf(sqrtf(hs), 1e-12f);
        const float hb0 = bfround(h2.x * rinv);
        const float hb1 = bfround(h2.y * rinv);
        float corr = 0.0f;
        for (int k = 0; k < NNEG; k += 64) {
            const int sj = ssi[k + lane];
            unsigned long long mm = __ballot(sj == yb);
            while (mm) {
                const int jj = (int)(__ffsll((long long)mm) - 1); mm &= mm - 1;
                const int j = k + jj;
                const unsigned int eu = en_bf[(size_t)j * 64 + lane];
                const float e0 = __uint_as_float(eu << 16);
                const float e1 = __uint_as_float(eu & 0xFFFF0000u);
                float d = hb0 * e0 + hb1 * e1;
                #pragma unroll
                for (int q = 1; q <= 32; q <<= 1) d += __shfl_xor(d, q);
                corr += __builtin_amdgcn_exp2f(fmaf(d, t2, fmaf(ln_samp[j], -L2E, -M2)));
            }
        }
        if (lane == b) s -= corr;
    }
    s = fmaxf(s, 0.0f);   // guard cancellation corner

    const float pa = pos_adj[r];
    const float stot = s + __builtin_amdgcn_exp2f(fmaf(pa, L2E, -M2));
    float per = (Mln + logf(stot) - pa) * w;

    #pragma unroll
    for (int msk = 1; msk < 64; msk <<= 1) {
        per += __shfl_xor(per, msk);
        w += __shfl_xor(w, msk);
    }
    if (lane == 0) red2[wave] = make_float2(per, w);
    __syncthreads();
    if (t == 0) {
        const float2 a = red2[0], b2 = red2[1], c = red2[2], d2 = red2[3];
        partials[blockIdx.x] = make_float2(a.x + b2.x + c.x + d2.x,
                                           a.y + b2.y + c.y + d2.y);
    }
}

// ---------------- finalize: deterministic reduction ----------------
__global__ __launch_bounds__(TPB) void sspe_finalize(
    const float2* __restrict__ partials, int n, float* __restrict__ out)
{
    __shared__ float ssum[TPB];
    __shared__ float scnt[TPB];
    const int t = threadIdx.x;
    float s = 0.0f, c = 0.0f;
    for (int i = t; i < n; i += TPB) {
        const float2 p = partials[i];
        s += p.x; c += p.y;
    }
    ssum[t] = s; scnt[t] = c;
    __syncthreads();
    for (int k = TPB / 2; k > 0; k >>= 1) {
        if (t < k) { ssum[t] += ssum[t + k]; scnt[t] += scnt[t + k]; }
        __syncthreads();
    }
    if (t == 0) out[0] = ssum[0] / fmaxf(scnt[0], 1.0f);
}

extern "C" void kernel_launch(void* const* d_in, const int* in_sizes, int n_in,
                              void* d_out, int out_size, void* d_ws, size_t ws_size,
                              hipStream_t stream) {
    const float* hidden = (const float*)d_in[0];
    const int*   yv     = (const int*)d_in[1];
    const float* embed  = (const float*)d_in[2];
    const float* sprobs = (const float*)d_in[3];
    const int*   sidx   = (const int*)d_in[4];
    const float* ltemp  = (const float*)d_in[5];
    float* out = (float*)d_out;

    const int nrows = in_sizes[1];                 // 65536
    const int vocab = in_sizes[3];                 // 100000
    const int bmw = (vocab + 31) / 32;
    const int nblocks = (nrows / RPB) * NSPLIT;    // 1024

    char* w = (char*)d_ws;
    size_t off = 0;
    unsigned int* en_bf = (unsigned int*)(w + off); off += (size_t)NNEG * D * 2;       // 512 KB
    float* ln_samp      = (float*)(w + off);        off += (size_t)NNEG * 4;           // 8 KB
    float* pos_adj      = (float*)(w + off);        off += (size_t)nrows * 4;          // 256 KB
    float* lsum         = (float*)(w + off);        off += (size_t)NSPLIT * nrows * 4; // 512 KB
    float2* partials    = (float2*)(w + off);       off += (size_t)(nrows / TPB) * 8;  // 2 KB
    unsigned int* bitmap = (unsigned int*)(w + off);

    sspe_clear<<<(bmw + TPB - 1) / TPB, TPB, 0, stream>>>(bitmap, bmw);
    sspe_prep<<<NNEG / 4, TPB, 0, stream>>>(embed, sprobs, sidx, en_bf, ln_samp, bitmap);
    sspe_main<<<nblocks, TPB, 0, stream>>>(hidden, yv, embed, sprobs, ltemp,
                                           en_bf, ln_samp, pos_adj, lsum, nrows);
    sspe_rows<<<nrows / TPB, TPB, 0, stream>>>(yv, ltemp, sidx, hidden, en_bf, ln_samp,
                                               bitmap, pos_adj, lsum, nrows, partials);
    sspe_finalize<<<1, TPB, 0, stream>>>(partials, nrows / TPB, out);
}